// Round 6
// baseline (542.147 us; speedup 1.0000x reference)
//
#include <hip/hip_runtime.h>
#include <stdint.h>

#define NB 4096
#define NT 48
#define NF 225
#define NH 128
#define NG 512   // 4*H
#define NK 256   // K padded 225->256 in xh layout
#define NCLS 100

typedef __attribute__((ext_vector_type(8))) _Float16 v8h;
typedef __attribute__((ext_vector_type(4))) _Float16 v4h;
typedef __attribute__((ext_vector_type(4))) float v4f;

__device__ __forceinline__ float fsig(float x) {
    return __builtin_amdgcn_rcpf(1.f + __expf(-x));
}
__device__ __forceinline__ float ftanh(float x) {
    return 2.f * __builtin_amdgcn_rcpf(1.f + __expf(-2.f * x)) - 1.f;
}

// global -> LDS direct copy, 16B per lane (dest = wave-uniform base, HW adds lane*16).
__device__ __forceinline__ void gld16(const void* g, void* l) {
    __builtin_amdgcn_global_load_lds(
        (const __attribute__((address_space(1))) void*)g,
        (__attribute__((address_space(3))) void*)l, 16, 0, 0);
}

// ---------------------------------------------------------------------------
// k_prep:
//  xh[t][b][256]   fp16, zero-padded K>=225, 16B chunks XOR-swizzled by (b&7)
//  wh[dir][512][256]    fp16 LINEAR (per-lane register-fragment gathers)
//  whh_h[dir][512][128] fp16 linear
//  bsum[dir][512] = b_ih + b_hh (fp32)
// ---------------------------------------------------------------------------
__global__ __launch_bounds__(256) void k_prep(
    const float* __restrict__ x,
    const float* __restrict__ wihf, const float* __restrict__ wihb,
    const float* __restrict__ whhf, const float* __restrict__ whhb,
    const float* __restrict__ bihf, const float* __restrict__ bhhf,
    const float* __restrict__ bihb, const float* __restrict__ bhhb,
    _Float16* __restrict__ xh, _Float16* __restrict__ wh,
    _Float16* __restrict__ whh_h, float* __restrict__ bsum)
{
    __shared__ __attribute__((aligned(16))) _Float16 ls[NT * NF + 16];
    const int bid = blockIdx.x;
    const int tid = threadIdx.x;

    if (bid < NB) {
        const float* src = x + (size_t)bid * (NT * NF);   // 43200B contiguous
        for (int i = tid; i < (NT * NF) / 4; i += 256) {
            const float4 v = ((const float4*)src)[i];
            v4h hv; hv[0] = (_Float16)v.x; hv[1] = (_Float16)v.y;
            hv[2] = (_Float16)v.z; hv[3] = (_Float16)v.w;
            *(v4h*)(ls + i * 4) = hv;
        }
        __syncthreads();
        const int key = bid & 7;
        for (int task = tid; task < NT * 32; task += 256) {
            const int t = task >> 5, c = task & 31;
            v8h hv;
#pragma unroll
            for (int e = 0; e < 8; ++e) {
                const int k = c * 8 + e;
                hv[e] = (k < NF) ? ls[t * NF + k] : (_Float16)0.f;
            }
            *(v8h*)(xh + ((size_t)t * NB + bid) * NK + ((c ^ key) << 3)) = hv;
        }
    } else if (bid < NB + 128) {
        const int r = (bid - NB) * 8 + (tid >> 5);   // 0..1023
        const int c = tid & 31;
        const int dir = r >> 9, n = r & 511;
        const float* src = (dir ? wihb : wihf) + (size_t)n * NF + c * 8;
        v8h hv;
#pragma unroll
        for (int i = 0; i < 8; ++i) {
            const int k = c * 8 + i;
            hv[i] = (k < NF) ? (_Float16)src[i] : (_Float16)0.f;
        }
        *(v8h*)(wh + (size_t)r * NK + (c << 3)) = hv;   // LINEAR
    } else if (bid < NB + 160) {
        const int base = (bid - NB - 128) * 4096 + tid;   // whh: 131072 elems
#pragma unroll
        for (int s = 0; s < 16; ++s) {
            const int i = base + s * 256;
            whh_h[i] = (_Float16)((i < 65536) ? whhf[i] : whhb[i - 65536]);
        }
    } else {
        for (int i = tid; i < 1024; i += 256) {
            const int dir = i >> 9, n = i & 511;
            bsum[i] = dir ? (bihb[n] + bhhb[n]) : (bihf[n] + bhhf[n]);
        }
    }
}

// ---------------------------------------------------------------------------
// k_fused: input GEMM + LSTM recurrence + hsum, one dispatch.
// Block = 32 b-rows x dir, 1024 threads (16 waves). Wave w owns n-cols
// [w*32, w*32+32) = gate (w>>2), hcol group (w&3)*32. Persistent B in VGPRs:
// 7 x-K-slices + 4 h-K-slices = 88 VGPR/wave (fits 128-reg cap at 4 w/EU).
// k=224 handled as rank-1 VALU term in combine. Gate recombination via
// 64KB LDS exchange (fp32, XOR-swizzled, conflict-free).
// ---------------------------------------------------------------------------
__global__ __launch_bounds__(1024, 4) void k_fused(
    const _Float16* __restrict__ xh,     // [48][4096][256] swizzled (b&7)
    const _Float16* __restrict__ wh,     // [2][512][256] linear
    const _Float16* __restrict__ whh_h,  // [2][512][128] linear
    const float* __restrict__ bsum,      // [2][512]
    float* __restrict__ hsum)            // [2][4096][128]
{
    __shared__ __attribute__((aligned(16))) _Float16 xb[2][32 * 256]; // 32KB
    __shared__ __attribute__((aligned(16))) _Float16 hb[2][32 * 128]; // 16KB
    __shared__ __attribute__((aligned(16))) float    exch[4 * 128 * 32]; // 64KB

    const int tid   = threadIdx.x;
    const int btile = blockIdx.x;        // 0..127
    const int dir   = blockIdx.y;
    const int rb    = btile * 32;
    const int lane  = tid & 63;
    const int w     = tid >> 6;          // 0..15
    const int l15   = lane & 15;
    const int grp   = lane >> 4;
    const int gate  = w >> 2;            // exch write gate

    // ---- persistent weight fragments: 32 n-cols per wave ----
    v8h bxw[7][2];   // x-part K-slices 0..6 (k 0..223)
    v8h bhw[4][2];   // h-part K-slices 0..3
    float bias[2];
#pragma unroll
    for (int nt = 0; nt < 2; ++nt) {
        const int n = w * 32 + nt * 16 + l15;
#pragma unroll
        for (int ks = 0; ks < 7; ++ks)
            bxw[ks][nt] = *(const v8h*)(wh + (size_t)(dir * NG + n) * NK
                                        + ks * 32 + grp * 8);
#pragma unroll
        for (int ks = 0; ks < 4; ++ks)
            bhw[ks][nt] = *(const v8h*)(whh_h + (size_t)(dir * NG + n) * NH
                                        + ks * 32 + grp * 8);
        bias[nt] = bsum[dir * NG + n];
    }

    // ---- combine-phase ownership: 4 b-rows x 1 hcol per thread ----
    const int hcolC = tid >> 3;          // 0..127
    const int b0    = (tid & 7) * 4;     // 0..28
    float w224g[4];
#pragma unroll
    for (int g = 0; g < 4; ++g)
        w224g[g] = (float)wh[(size_t)(dir * NG + g * NH + hcolC) * NK + 224];

    float c0[4], hs0[4];
#pragma unroll
    for (int j = 0; j < 4; ++j) { c0[j] = 0.f; hs0[j] = 0.f; }

    // stage: 16 waves x 1KB = 16KB = 32 rows x 512B (contiguous slab)
    auto stage = [&](int tx, int buf) {
        const char* src = (const char*)(xh + ((size_t)tx * NB + rb) * NK);
        gld16(src + (w << 10) + lane * 16, (char*)xb[buf] + (w << 10));
    };

    stage(dir ? (NT - 1) : 0, 0);
    __syncthreads();

    int cur = 0, hc = 0;
#pragma unroll 1
    for (int s = 0; s < NT; ++s) {
        if (s + 1 < NT)
            stage(dir ? (NT - 2 - s) : (s + 1), cur ^ 1);   // async prefetch

        // ---- MFMA phase ----
        v4f acc[2][2];
#pragma unroll
        for (int m = 0; m < 2; ++m)
#pragma unroll
            for (int nt = 0; nt < 2; ++nt)
                acc[m][nt] = (v4f){bias[nt], bias[nt], bias[nt], bias[nt]};

#pragma unroll
        for (int ks = 0; ks < 7; ++ks) {
            v8h af0 = *(const v8h*)((const char*)xb[cur] + (l15 << 9)
                        + (((ks * 4 + grp) ^ (l15 & 7)) << 4));
            v8h af1 = *(const v8h*)((const char*)xb[cur] + ((16 + l15) << 9)
                        + (((ks * 4 + grp) ^ (l15 & 7)) << 4));
            acc[0][0] = __builtin_amdgcn_mfma_f32_16x16x32_f16(af0, bxw[ks][0], acc[0][0], 0, 0, 0);
            acc[1][0] = __builtin_amdgcn_mfma_f32_16x16x32_f16(af1, bxw[ks][0], acc[1][0], 0, 0, 0);
            acc[0][1] = __builtin_amdgcn_mfma_f32_16x16x32_f16(af0, bxw[ks][1], acc[0][1], 0, 0, 0);
            acc[1][1] = __builtin_amdgcn_mfma_f32_16x16x32_f16(af1, bxw[ks][1], acc[1][1], 0, 0, 0);
        }
        if (s > 0) {
#pragma unroll
            for (int ks = 0; ks < 4; ++ks) {
                v8h ah0 = *(const v8h*)((const char*)hb[hc] + (l15 << 8)
                            + (((ks * 4 + grp) ^ (l15 & 7)) << 4));
                v8h ah1 = *(const v8h*)((const char*)hb[hc] + ((16 + l15) << 8)
                            + (((ks * 4 + grp) ^ (l15 & 7)) << 4));
                acc[0][0] = __builtin_amdgcn_mfma_f32_16x16x32_f16(ah0, bhw[ks][0], acc[0][0], 0, 0, 0);
                acc[1][0] = __builtin_amdgcn_mfma_f32_16x16x32_f16(ah1, bhw[ks][0], acc[1][0], 0, 0, 0);
                acc[0][1] = __builtin_amdgcn_mfma_f32_16x16x32_f16(ah0, bhw[ks][1], acc[0][1], 0, 0, 0);
                acc[1][1] = __builtin_amdgcn_mfma_f32_16x16x32_f16(ah1, bhw[ks][1], acc[1][1], 0, 0, 0);
            }
        }

        // ---- exchange write: pre-activation gate values (fp32, swizzled) ----
#pragma unroll
        for (int m = 0; m < 2; ++m)
#pragma unroll
            for (int nt = 0; nt < 2; ++nt) {
                const int hcolW = (w & 3) * 32 + nt * 16 + l15;
                const int fi = (m * 16 + grp * 4) ^ ((hcolW & 7) << 2);
                *(v4f*)(exch + (gate << 12) + (hcolW << 5) + fi) = acc[m][nt];
            }
        __syncthreads();   // exch visible (also drains prefetch vmcnt)

        // ---- combine phase: gates -> c,h update (4 elements/thread) ----
        v4f pg[4];
#pragma unroll
        for (int g = 0; g < 4; ++g)
            pg[g] = *(const v4f*)(exch + (g << 12) + (hcolC << 5)
                                  + (b0 ^ ((hcolC & 7) << 2)));
        float xv[4];
#pragma unroll
        for (int j = 0; j < 4; ++j) {
            const int row = b0 + j;
            xv[j] = (float)*(const _Float16*)((const char*)xb[cur]
                      + (row << 9) + ((28 ^ (row & 7)) << 4));   // k=224
        }
#pragma unroll
        for (int j = 0; j < 4; ++j) {
            const float iv = fsig(pg[0][j] + xv[j] * w224g[0]);
            const float fv = fsig(pg[1][j] + xv[j] * w224g[1]);
            const float gv = ftanh(pg[2][j] + xv[j] * w224g[2]);
            const float ov = fsig(pg[3][j] + xv[j] * w224g[3]);
            const float c = fv * c0[j] + iv * gv;
            c0[j] = c;
            const float h = ov * ftanh(c);
            hs0[j] += h;
            const int row = b0 + j;
            *(_Float16*)((char*)hb[hc ^ 1] + (row << 8)
                         + ((hcolC << 1) ^ ((row & 7) << 4))) = (_Float16)h;
        }
        __syncthreads();   // hb ready for next step's h-MFMA
        cur ^= 1; hc ^= 1;
    }

#pragma unroll
    for (int j = 0; j < 4; ++j)
        hsum[((size_t)dir * NB + rb + b0 + j) * NH + hcolC] = hs0[j];
}

// ---------------------------------------------------------------------------
// k_head: pooled = hsum/T ; h1 = relu(pooled@fc1_w^T+b) ; out = h1@fc2_w^T+b
// ---------------------------------------------------------------------------
__global__ __launch_bounds__(128) void k_head(
    const float* __restrict__ hsum,
    const float* __restrict__ fc1w, const float* __restrict__ fc1b,
    const float* __restrict__ fc2w, const float* __restrict__ fc2b,
    float* __restrict__ out)
{
    __shared__ __attribute__((aligned(16))) float pooled[16][256];
    __shared__ __attribute__((aligned(16))) float h1s[16][128];
    __shared__ __attribute__((aligned(16))) char wbuf[65536];

    const int tid = threadIdx.x;
    const int rb  = blockIdx.x * 16;

    for (int i = tid; i < 16 * 256; i += 128) {
        const int r = i >> 8, c = i & 255;
        const float v = (c < 128)
            ? hsum[(size_t)(rb + r) * NH + c]
            : hsum[((size_t)NB + rb + r) * NH + (c - 128)];
        pooled[r][c] = v * (1.f / (float)NT);
    }
    for (int i = tid; i < 128 * 64; i += 128) {
        const int j = i >> 6, kq = i & 63;
        const float4 v = *(const float4*)(fc1w + (size_t)j * 256 + (kq << 2));
        v4h pv; pv[0] = (_Float16)v.x; pv[1] = (_Float16)v.y;
        pv[2] = (_Float16)v.z; pv[3] = (_Float16)v.w;
        const int byo = (j << 9) + ((kq << 3) ^ (((j >> 3) & 7) << 4));
        *(v4h*)(wbuf + byo) = pv;
    }
    __syncthreads();

    const int rgrp = tid >> 4;
    const int joct = tid & 15;
    const int r0 = rgrp * 2;
    const int j0 = joct * 8;

    float a1[2][8];
#pragma unroll
    for (int rr = 0; rr < 2; ++rr)
#pragma unroll
        for (int jo = 0; jo < 8; ++jo) a1[rr][jo] = 0.f;

    for (int kc = 0; kc < 32; ++kc) {
        const int k = kc << 3;
        float pv[2][8];
#pragma unroll
        for (int rr = 0; rr < 2; ++rr) {
            const float4 pa = *(const float4*)&pooled[r0 + rr][k];
            const float4 pb = *(const float4*)&pooled[r0 + rr][k + 4];
            pv[rr][0] = pa.x; pv[rr][1] = pa.y; pv[rr][2] = pa.z; pv[rr][3] = pa.w;
            pv[rr][4] = pb.x; pv[rr][5] = pb.y; pv[rr][6] = pb.z; pv[rr][7] = pb.w;
        }
#pragma unroll
        for (int jo = 0; jo < 8; ++jo) {
            const int j = j0 + jo;
            const int byo = (j << 9) + ((k << 1) ^ (((j >> 3) & 7) << 4));
            const v8h wv = *(const v8h*)(wbuf + byo);
#pragma unroll
            for (int i = 0; i < 8; ++i) {
                const float wf = (float)wv[i];
#pragma unroll
                for (int rr = 0; rr < 2; ++rr)
                    a1[rr][jo] += pv[rr][i] * wf;
            }
        }
    }
#pragma unroll
    for (int rr = 0; rr < 2; ++rr)
#pragma unroll
        for (int jo = 0; jo < 8; ++jo) {
            const int j = j0 + jo;
            const float v = a1[rr][jo] + fc1b[j];
            h1s[r0 + rr][j] = v > 0.f ? v : 0.f;
        }
    __syncthreads();

    for (int i = tid; i < 100 * 32; i += 128) {
        const int j = i >> 5, kq = i & 31;
        const float4 v = *(const float4*)(fc2w + (size_t)j * 128 + (kq << 2));
        const int byo = (j << 9) + ((kq << 4) ^ (((j >> 3) & 7) << 4));
        *(float4*)(wbuf + byo) = v;
    }
    __syncthreads();

    if (j0 < 100) {
        float a2[2][8];
#pragma unroll
        for (int rr = 0; rr < 2; ++rr)
#pragma unroll
            for (int jo = 0; jo < 8; ++jo) a2[rr][jo] = 0.f;

        for (int kc = 0; kc < 16; ++kc) {
            const int k = kc << 3;
            float hv[2][8];
#pragma unroll
            for (int rr = 0; rr < 2; ++rr) {
                const float4 ha = *(const float4*)&h1s[r0 + rr][k];
                const float4 hbv = *(const float4*)&h1s[r0 + rr][k + 4];
                hv[rr][0] = ha.x; hv[rr][1] = ha.y; hv[rr][2] = ha.z; hv[rr][3] = ha.w;
                hv[rr][4] = hbv.x; hv[rr][5] = hbv.y; hv[rr][6] = hbv.z; hv[rr][7] = hbv.w;
            }
#pragma unroll
            for (int jo = 0; jo < 8; ++jo) {
                const int j = j0 + jo;
                if (j < 100) {
                    const int sw = ((j >> 3) & 7) << 4;
                    const float4 wa = *(const float4*)(wbuf + (j << 9) + ((k << 2) ^ sw));
                    const float4 wb = *(const float4*)(wbuf + (j << 9) + (((k + 4) << 2) ^ sw));
#pragma unroll
                    for (int rr = 0; rr < 2; ++rr) {
                        a2[rr][jo] += hv[rr][0] * wa.x + hv[rr][1] * wa.y
                                    + hv[rr][2] * wa.z + hv[rr][3] * wa.w
                                    + hv[rr][4] * wb.x + hv[rr][5] * wb.y
                                    + hv[rr][6] * wb.z + hv[rr][7] * wb.w;
                    }
                }
            }
        }
#pragma unroll
        for (int rr = 0; rr < 2; ++rr)
#pragma unroll
            for (int jo = 0; jo < 8; ++jo) {
                const int j = j0 + jo;
                if (j < 100)
                    out[(size_t)(rb + r0 + rr) * NCLS + j] = a2[rr][jo] + fc2b[j];
            }
    }
}

// ---------------------------------------------------------------------------
extern "C" void kernel_launch(void* const* d_in, const int* in_sizes, int n_in,
                              void* d_out, int out_size, void* d_ws, size_t ws_size,
                              hipStream_t stream)
{
    (void)in_sizes; (void)n_in; (void)out_size; (void)ws_size;
    const float* x    = (const float*)d_in[0];
    const float* wihf = (const float*)d_in[1];
    const float* whhf = (const float*)d_in[2];
    const float* bihf = (const float*)d_in[3];
    const float* bhhf = (const float*)d_in[4];
    const float* wihb = (const float*)d_in[5];
    const float* whhb = (const float*)d_in[6];
    const float* bihb = (const float*)d_in[7];
    const float* bhhb = (const float*)d_in[8];
    const float* fc1w = (const float*)d_in[9];
    const float* fc1b = (const float*)d_in[10];
    const float* fc2w = (const float*)d_in[11];
    const float* fc2b = (const float*)d_in[12];
    float* out = (float*)d_out;

    char* ws = (char*)d_ws;
    float*     hs    = (float*)ws;                                    // 4 MB
    size_t off = (size_t)4 * 1024 * 1024;
    _Float16*  xh    = (_Float16*)(ws + off); off += (size_t)NB * NT * NK * 2; // 100.7 MB
    _Float16*  wh    = (_Float16*)(ws + off); off += (size_t)2 * NG * NK * 2;
    _Float16*  whh_h = (_Float16*)(ws + off); off += (size_t)2 * NG * NH * 2;
    float*     bsum  = (float*)(ws + off);    off += 1024 * 4;

    k_prep<<<dim3(NB + 161), dim3(256), 0, stream>>>(
        x, wihf, wihb, whhf, whhb, bihf, bhhf, bihb, bhhb,
        xh, wh, whh_h, bsum);
    k_fused<<<dim3(128, 2), dim3(1024), 0, stream>>>(
        xh, wh, whh_h, bsum, hs);
    k_head<<<dim3(256), dim3(128), 0, stream>>>(hs, fc1w, fc1b, fc2w, fc2b, out);
}

// Round 7
// 360.538 us; speedup vs baseline: 1.5037x; 1.5037x over previous
//
#include <hip/hip_runtime.h>
#include <stdint.h>

#define NB 4096
#define NT 48
#define NF 225
#define NH 128
#define NG 512   // 4*H
#define NK 256   // K padded 225->256 in xh layout
#define NCLS 100

typedef __attribute__((ext_vector_type(8))) _Float16 v8h;
typedef __attribute__((ext_vector_type(4))) _Float16 v4h;
typedef __attribute__((ext_vector_type(4))) float v4f;
typedef __attribute__((ext_vector_type(16))) float v16f;

__device__ __forceinline__ float fsig(float x) {
    return __builtin_amdgcn_rcpf(1.f + __expf(-x));
}
__device__ __forceinline__ float ftanh(float x) {
    return 2.f * __builtin_amdgcn_rcpf(1.f + __expf(-2.f * x)) - 1.f;
}

// global -> LDS direct copy, 16B per lane (dest = wave-uniform base, HW adds lane*16).
__device__ __forceinline__ void gld16(const void* g, void* l) {
    __builtin_amdgcn_global_load_lds(
        (const __attribute__((address_space(1))) void*)g,
        (__attribute__((address_space(3))) void*)l, 16, 0, 0);
}

// ---------------------------------------------------------------------------
// k_prep:
//  xh[t][b][256]       fp16, zero-padded, 16B chunks XOR-swizzled by (b&31)
//  wh[dir][512][256]   fp16 LINEAR (per-lane register-fragment gathers; [224] used for rank-1)
//  whh_h[dir][512][128] fp16 linear
//  wxk[dir][6][512][8] fp16: x-weight k=176..223 as 6 planes (slice,khalf) for LDS-B
//  bsum[dir][512] = b_ih + b_hh (fp32)
// ---------------------------------------------------------------------------
__global__ __launch_bounds__(256) void k_prep(
    const float* __restrict__ x,
    const float* __restrict__ wihf, const float* __restrict__ wihb,
    const float* __restrict__ whhf, const float* __restrict__ whhb,
    const float* __restrict__ bihf, const float* __restrict__ bhhf,
    const float* __restrict__ bihb, const float* __restrict__ bhhb,
    _Float16* __restrict__ xh, _Float16* __restrict__ wh,
    _Float16* __restrict__ whh_h, _Float16* __restrict__ wxk,
    float* __restrict__ bsum)
{
    __shared__ __attribute__((aligned(16))) _Float16 ls[NT * NF + 16];
    const int bid = blockIdx.x;
    const int tid = threadIdx.x;

    if (bid < NB) {
        const float* src = x + (size_t)bid * (NT * NF);   // 43200B contiguous
        for (int i = tid; i < (NT * NF) / 4; i += 256) {
            const float4 v = ((const float4*)src)[i];
            v4h hv; hv[0] = (_Float16)v.x; hv[1] = (_Float16)v.y;
            hv[2] = (_Float16)v.z; hv[3] = (_Float16)v.w;
            *(v4h*)(ls + i * 4) = hv;
        }
        __syncthreads();
        const int key = bid & 31;                         // 5-bit key (32-row tiles)
        for (int task = tid; task < NT * 32; task += 256) {
            const int t = task >> 5, c = task & 31;
            v8h hv;
#pragma unroll
            for (int e = 0; e < 8; ++e) {
                const int k = c * 8 + e;
                hv[e] = (k < NF) ? ls[t * NF + k] : (_Float16)0.f;
            }
            *(v8h*)(xh + ((size_t)t * NB + bid) * NK + ((c ^ key) << 3)) = hv;
        }
    } else if (bid < NB + 128) {
        const int r = (bid - NB) * 8 + (tid >> 5);   // 0..1023 = dir*512+n
        const int c = tid & 31;
        const int dir = r >> 9, n = r & 511;
        const float* src = (dir ? wihb : wihf) + (size_t)n * NF + c * 8;
        v8h hv;
#pragma unroll
        for (int i = 0; i < 8; ++i) {
            const int k = c * 8 + i;
            hv[i] = (k < NF) ? (_Float16)src[i] : (_Float16)0.f;
        }
        *(v8h*)(wh + (size_t)r * NK + (c << 3)) = hv;   // LINEAR
    } else if (bid < NB + 160) {
        const int base = (bid - NB - 128) * 4096 + tid;   // whh: 131072 elems
#pragma unroll
        for (int s = 0; s < 16; ++s) {
            const int i = base + s * 256;
            whh_h[i] = (_Float16)((i < 65536) ? whhf[i] : whhb[i - 65536]);
        }
    } else if (bid < NB + 168) {
        // wxk: 2 dir x 6 planes x 512 n x 8 k (k_global = 176 + p*8 .. +8)
        for (int r = 0; r < 3; ++r) {
            const int e = (bid - NB - 160) * 768 + r * 256 + tid;   // 0..6143
            const int dir = e / 3072;
            const int rem = e - dir * 3072;
            const int p = rem >> 9, n = rem & 511;
            const float* src = (dir ? wihb : wihf) + (size_t)n * NF + 176 + p * 8;
            v8h hv;
#pragma unroll
            for (int kk = 0; kk < 8; ++kk) hv[kk] = (_Float16)src[kk];
            *(v8h*)(wxk + ((size_t)(dir * 6 + p) * 512 + n) * 8) = hv;
        }
    } else {
        for (int i = tid; i < 1024; i += 256) {
            const int dir = i >> 9, n = i & 511;
            bsum[i] = dir ? (bihb[n] + bhhb[n]) : (bihf[n] + bhhf[n]);
        }
    }
}

// ---------------------------------------------------------------------------
// k_fused: input GEMM + LSTM recurrence + hsum, one dispatch.
// Block = 32 b-rows x dir, 512 thr (8 waves), 1 block/CU, waves_per_eu pinned
// to 2 so the allocator can use the full 256-VGPR budget (~235 demand).
// Wave w owns cols [w*64, w*64+64) as 2 x 32-col 32x32x16 fragments.
// B in VGPRs: x k0..175 (11 slices) + h K=128 (8 slices) = 152 regs.
// x k176..223 from 48KB LDS plane buffer; k=224 rank-1 in combine.
// Gate recombination via 64KB fp32 LDS exchange (XOR-swizzled).
// ---------------------------------------------------------------------------
__global__ void __launch_bounds__(512)
__attribute__((amdgpu_waves_per_eu(2, 2)))
k_fused(
    const _Float16* __restrict__ xh,     // [48][4096][256] swizzled (b&31)
    const _Float16* __restrict__ wh,     // [2][512][256] linear
    const _Float16* __restrict__ whh_h,  // [2][512][128] linear
    const _Float16* __restrict__ wxk,    // [2][6][512][8]
    const float* __restrict__ bsum,      // [2][512]
    float* __restrict__ hsum)            // [2][4096][128]
{
    __shared__ __attribute__((aligned(16))) _Float16 xb[2][32 * 256]; // 32KB
    __shared__ __attribute__((aligned(16))) _Float16 hb[32 * 128];    // 8KB
    __shared__ __attribute__((aligned(16))) _Float16 bx4[6 * 512 * 8];// 48KB
    __shared__ __attribute__((aligned(16))) float    exch[4 * 128 * 32]; // 64KB
    __shared__ float wtab[512];                                       // 2KB

    const int tid   = threadIdx.x;
    const int btile = blockIdx.x;        // 0..127
    const int dir   = blockIdx.y;
    const int rb    = btile * 32;
    const int lane  = tid & 63;
    const int w     = tid >> 6;          // 0..7
    const int col32 = lane & 31;         // A-row / B-col / C-col
    const int khalf = lane >> 5;

    // one-time LDS preload of k176..223 B-planes (48 segs of 1KB)
#pragma unroll
    for (int j = 0; j < 6; ++j) {
        const int seg = w * 6 + j;
        gld16((const char*)wxk + (size_t)dir * 49152 + (seg << 10) + lane * 16,
              (char*)bx4 + (seg << 10));
    }
    if (tid < 512)
        wtab[tid] = (float)wh[((size_t)(dir * NG + tid)) * NK + 224];

    // persistent B fragments
    v8h bxr[2][11], bhr[2][8];
    float bias_[2];
#pragma unroll
    for (int f = 0; f < 2; ++f) {
        const int n = (w * 2 + f) * 32 + col32;
        const _Float16* pw = wh + (size_t)(dir * NG + n) * NK + khalf * 8;
#pragma unroll
        for (int s = 0; s < 11; ++s) bxr[f][s] = *(const v8h*)(pw + s * 16);
        const _Float16* ph = whh_h + (size_t)(dir * NG + n) * NH + khalf * 8;
#pragma unroll
        for (int s = 0; s < 8; ++s) bhr[f][s] = *(const v8h*)(ph + s * 16);
        bias_[f] = bsum[dir * NG + n];
    }

    // combine ownership: row rowC, hcols qC*8..+7
    const int rowC = tid & 31;
    const int qC   = tid >> 5;           // 0..15
    float c0[8], hs0[8];
#pragma unroll
    for (int i = 0; i < 8; ++i) { c0[i] = 0.f; hs0[i] = 0.f; }

    auto stage = [&](int tx, int buf) {
        const char* src = (const char*)(xh + ((size_t)tx * NB + rb) * NK);
#pragma unroll
        for (int c = 0; c < 2; ++c) {
            const int seg = w * 2 + c;
            gld16(src + (seg << 10) + lane * 16, (char*)xb[buf] + (seg << 10));
        }
    };

    stage(dir ? (NT - 1) : 0, 0);
    __syncthreads();   // preloads + stage drained

    int cur = 0;
#pragma unroll 1
    for (int s = 0; s < NT; ++s) {
        if (s + 1 < NT)
            stage(dir ? (NT - 2 - s) : (s + 1), cur ^ 1);   // async prefetch

        v16f a0, a1;
#pragma unroll
        for (int r = 0; r < 16; ++r) { a0[r] = bias_[0]; a1[r] = bias_[1]; }

        const char* xbc = (const char*)xb[cur];
        // x-part: 11 register-B slices (k 0..175)
#pragma unroll
        for (int ks = 0; ks < 11; ++ks) {
            const v8h af = *(const v8h*)(xbc + (col32 << 9)
                             + ((((ks << 1) + khalf) ^ col32) << 4));
            a0 = __builtin_amdgcn_mfma_f32_32x32x16_f16(af, bxr[0][ks], a0, 0, 0, 0);
            a1 = __builtin_amdgcn_mfma_f32_32x32x16_f16(af, bxr[1][ks], a1, 0, 0, 0);
        }
        // x-part: 3 LDS-B slices (k 176..223)
#pragma unroll
        for (int ks = 0; ks < 3; ++ks) {
            const v8h af = *(const v8h*)(xbc + (col32 << 9)
                             + (((22 + (ks << 1) + khalf) ^ col32) << 4));
            const int p = ks * 2 + khalf;
            const v8h b0v = *(const v8h*)((const char*)bx4 + (p << 13)
                              + (((w * 2 + 0) * 32 + col32) << 4));
            const v8h b1v = *(const v8h*)((const char*)bx4 + (p << 13)
                              + (((w * 2 + 1) * 32 + col32) << 4));
            a0 = __builtin_amdgcn_mfma_f32_32x32x16_f16(af, b0v, a0, 0, 0, 0);
            a1 = __builtin_amdgcn_mfma_f32_32x32x16_f16(af, b1v, a1, 0, 0, 0);
        }
        // h-part: 8 register-B slices (K=128)
        if (s > 0) {
#pragma unroll
            for (int ks = 0; ks < 8; ++ks) {
                const v8h ah = *(const v8h*)((const char*)hb + (col32 << 8)
                                 + ((((ks << 1) + khalf) ^ (col32 & 15)) << 4));
                a0 = __builtin_amdgcn_mfma_f32_32x32x16_f16(ah, bhr[0][ks], a0, 0, 0, 0);
                a1 = __builtin_amdgcn_mfma_f32_32x32x16_f16(ah, bhr[1][ks], a1, 0, 0, 0);
            }
        }

        // exchange write: fp32 pre-activations, v4f, XOR-swizzled
        {
            const int n0 = (w * 2 + 0) * 32 + col32;
            char* e0 = (char*)exch + ((n0 >> 7) << 14) + ((n0 & 127) << 7);
            const int sw0 = ((n0 & 7) << 4);
#pragma unroll
            for (int G = 0; G < 4; ++G) {
                const int r0 = G * 8 + khalf * 4;
                v4f val; val[0] = a0[4*G]; val[1] = a0[4*G+1];
                val[2] = a0[4*G+2]; val[3] = a0[4*G+3];
                *(v4f*)(e0 + ((r0 << 2) ^ sw0)) = val;
            }
            const int n1 = (w * 2 + 1) * 32 + col32;
            char* e1 = (char*)exch + ((n1 >> 7) << 14) + ((n1 & 127) << 7);
            const int sw1 = ((n1 & 7) << 4);
#pragma unroll
            for (int G = 0; G < 4; ++G) {
                const int r0 = G * 8 + khalf * 4;
                v4f val; val[0] = a1[4*G]; val[1] = a1[4*G+1];
                val[2] = a1[4*G+2]; val[3] = a1[4*G+3];
                *(v4f*)(e1 + ((r0 << 2) ^ sw1)) = val;
            }
        }
        __syncthreads();   // exch visible; prefetch vmcnt drained

        // combine: 8 h-elements per thread, rank-1 k=224 folded in
        const float xv = (float)*(const _Float16*)(xbc + (rowC << 9)
                            + ((28 ^ rowC) << 4));
        v8h hop;
#pragma unroll
        for (int i = 0; i < 8; ++i) {
            const int hcol = qC * 8 + i;
            const int off = (hcol << 7) + (((rowC << 2)) ^ ((hcol & 7) << 4));
            const float p0 = *(const float*)((const char*)exch + off)
                             + xv * wtab[hcol];
            const float p1 = *(const float*)((const char*)exch + 16384 + off)
                             + xv * wtab[128 + hcol];
            const float p2 = *(const float*)((const char*)exch + 32768 + off)
                             + xv * wtab[256 + hcol];
            const float p3 = *(const float*)((const char*)exch + 49152 + off)
                             + xv * wtab[384 + hcol];
            const float iv = fsig(p0);
            const float fv = fsig(p1);
            const float gv = ftanh(p2);
            const float ov = fsig(p3);
            const float c = fv * c0[i] + iv * gv;
            c0[i] = c;
            const float h = ov * ftanh(c);
            hs0[i] += h;
            hop[i] = (_Float16)h;
        }
        *(v8h*)((char*)hb + (rowC << 8) + ((qC ^ (rowC & 15)) << 4)) = hop;
        __syncthreads();   // hb ready for next step
        cur ^= 1;
    }

    float* hp = hsum + ((size_t)dir * NB + rb + rowC) * NH + qC * 8;
#pragma unroll
    for (int i = 0; i < 8; ++i) hp[i] = hs0[i];
}

// ---------------------------------------------------------------------------
// k_head: pooled = hsum/T ; h1 = relu(pooled@fc1_w^T+b) ; out = h1@fc2_w^T+b
// ---------------------------------------------------------------------------
__global__ __launch_bounds__(128) void k_head(
    const float* __restrict__ hsum,
    const float* __restrict__ fc1w, const float* __restrict__ fc1b,
    const float* __restrict__ fc2w, const float* __restrict__ fc2b,
    float* __restrict__ out)
{
    __shared__ __attribute__((aligned(16))) float pooled[16][256];
    __shared__ __attribute__((aligned(16))) float h1s[16][128];
    __shared__ __attribute__((aligned(16))) char wbuf[65536];

    const int tid = threadIdx.x;
    const int rb  = blockIdx.x * 16;

    for (int i = tid; i < 16 * 256; i += 128) {
        const int r = i >> 8, c = i & 255;
        const float v = (c < 128)
            ? hsum[(size_t)(rb + r) * NH + c]
            : hsum[((size_t)NB + rb + r) * NH + (c - 128)];
        pooled[r][c] = v * (1.f / (float)NT);
    }
    for (int i = tid; i < 128 * 64; i += 128) {
        const int j = i >> 6, kq = i & 63;
        const float4 v = *(const float4*)(fc1w + (size_t)j * 256 + (kq << 2));
        v4h pv; pv[0] = (_Float16)v.x; pv[1] = (_Float16)v.y;
        pv[2] = (_Float16)v.z; pv[3] = (_Float16)v.w;
        const int byo = (j << 9) + ((kq << 3) ^ (((j >> 3) & 7) << 4));
        *(v4h*)(wbuf + byo) = pv;
    }
    __syncthreads();

    const int rgrp = tid >> 4;
    const int joct = tid & 15;
    const int r0 = rgrp * 2;
    const int j0 = joct * 8;

    float a1[2][8];
#pragma unroll
    for (int rr = 0; rr < 2; ++rr)
#pragma unroll
        for (int jo = 0; jo < 8; ++jo) a1[rr][jo] = 0.f;

    for (int kc = 0; kc < 32; ++kc) {
        const int k = kc << 3;
        float pv[2][8];
#pragma unroll
        for (int rr = 0; rr < 2; ++rr) {
            const float4 pa = *(const float4*)&pooled[r0 + rr][k];
            const float4 pb = *(const float4*)&pooled[r0 + rr][k + 4];
            pv[rr][0] = pa.x; pv[rr][1] = pa.y; pv[rr][2] = pa.z; pv[rr][3] = pa.w;
            pv[rr][4] = pb.x; pv[rr][5] = pb.y; pv[rr][6] = pb.z; pv[rr][7] = pb.w;
        }
#pragma unroll
        for (int jo = 0; jo < 8; ++jo) {
            const int j = j0 + jo;
            const int byo = (j << 9) + ((k << 1) ^ (((j >> 3) & 7) << 4));
            const v8h wv = *(const v8h*)(wbuf + byo);
#pragma unroll
            for (int i = 0; i < 8; ++i) {
                const float wf = (float)wv[i];
#pragma unroll
                for (int rr = 0; rr < 2; ++rr)
                    a1[rr][jo] += pv[rr][i] * wf;
            }
        }
    }
#pragma unroll
    for (int rr = 0; rr < 2; ++rr)
#pragma unroll
        for (int jo = 0; jo < 8; ++jo) {
            const int j = j0 + jo;
            const float v = a1[rr][jo] + fc1b[j];
            h1s[r0 + rr][j] = v > 0.f ? v : 0.f;
        }
    __syncthreads();

    for (int i = tid; i < 100 * 32; i += 128) {
        const int j = i >> 5, kq = i & 31;
        const float4 v = *(const float4*)(fc2w + (size_t)j * 128 + (kq << 2));
        const int byo = (j << 9) + ((kq << 4) ^ (((j >> 3) & 7) << 4));
        *(float4*)(wbuf + byo) = v;
    }
    __syncthreads();

    if (j0 < 100) {
        float a2[2][8];
#pragma unroll
        for (int rr = 0; rr < 2; ++rr)
#pragma unroll
            for (int jo = 0; jo < 8; ++jo) a2[rr][jo] = 0.f;

        for (int kc = 0; kc < 16; ++kc) {
            const int k = kc << 3;
            float hv[2][8];
#pragma unroll
            for (int rr = 0; rr < 2; ++rr) {
                const float4 ha = *(const float4*)&h1s[r0 + rr][k];
                const float4 hbv = *(const float4*)&h1s[r0 + rr][k + 4];
                hv[rr][0] = ha.x; hv[rr][1] = ha.y; hv[rr][2] = ha.z; hv[rr][3] = ha.w;
                hv[rr][4] = hbv.x; hv[rr][5] = hbv.y; hv[rr][6] = hbv.z; hv[rr][7] = hbv.w;
            }
#pragma unroll
            for (int jo = 0; jo < 8; ++jo) {
                const int j = j0 + jo;
                if (j < 100) {
                    const int sw = ((j >> 3) & 7) << 4;
                    const float4 wa = *(const float4*)(wbuf + (j << 9) + ((k << 2) ^ sw));
                    const float4 wb = *(const float4*)(wbuf + (j << 9) + (((k + 4) << 2) ^ sw));
#pragma unroll
                    for (int rr = 0; rr < 2; ++rr) {
                        a2[rr][jo] += hv[rr][0] * wa.x + hv[rr][1] * wa.y
                                    + hv[rr][2] * wa.z + hv[rr][3] * wa.w
                                    + hv[rr][4] * wb.x + hv[rr][5] * wb.y
                                    + hv[rr][6] * wb.z + hv[rr][7] * wb.w;
                    }
                }
            }
        }
#pragma unroll
        for (int rr = 0; rr < 2; ++rr)
#pragma unroll
            for (int jo = 0; jo < 8; ++jo) {
                const int j = j0 + jo;
                if (j < 100)
                    out[(size_t)(rb + r0 + rr) * NCLS + j] = a2[rr][jo] + fc2b[j];
            }
    }
}

// ---------------------------------------------------------------------------
extern "C" void kernel_launch(void* const* d_in, const int* in_sizes, int n_in,
                              void* d_out, int out_size, void* d_ws, size_t ws_size,
                              hipStream_t stream)
{
    (void)in_sizes; (void)n_in; (void)out_size; (void)ws_size;
    const float* x    = (const float*)d_in[0];
    const float* wihf = (const float*)d_in[1];
    const float* whhf = (const float*)d_in[2];
    const float* bihf = (const float*)d_in[3];
    const float* bhhf = (const float*)d_in[4];
    const float* wihb = (const float*)d_in[5];
    const float* whhb = (const float*)d_in[6];
    const float* bihb = (const float*)d_in[7];
    const float* bhhb = (const float*)d_in[8];
    const float* fc1w = (const float*)d_in[9];
    const float* fc1b = (const float*)d_in[10];
    const float* fc2w = (const float*)d_in[11];
    const float* fc2b = (const float*)d_in[12];
    float* out = (float*)d_out;

    char* ws = (char*)d_ws;
    float*     hs    = (float*)ws;                                    // 4 MB
    size_t off = (size_t)4 * 1024 * 1024;
    _Float16*  xh    = (_Float16*)(ws + off); off += (size_t)NB * NT * NK * 2; // 100.7 MB
    _Float16*  wh    = (_Float16*)(ws + off); off += (size_t)2 * NG * NK * 2;
    _Float16*  whh_h = (_Float16*)(ws + off); off += (size_t)2 * NG * NH * 2;
    _Float16*  wxk   = (_Float16*)(ws + off); off += (size_t)2 * 6 * 512 * 8 * 2;
    float*     bsum  = (float*)(ws + off);    off += 1024 * 4;

    k_prep<<<dim3(NB + 169), dim3(256), 0, stream>>>(
        x, wihf, wihb, whhf, whhb, bihf, bhhf, bihb, bhhb,
        xh, wh, whh_h, wxk, bsum);
    k_fused<<<dim3(128, 2), dim3(512), 0, stream>>>(
        xh, wh, whh_h, wxk, bsum, hs);
    k_head<<<dim3(256), dim3(128), 0, stream>>>(hs, fc1w, fc1b, fc2w, fc2b, out);
}